// Round 1
// 1119.596 us; speedup vs baseline: 1.2461x; 1.2461x over previous
//
#include <hip/hip_runtime.h>
#include <hip/hip_bf16.h>
#include <math.h>

#define M_ROWS   2048
#define N_VOCAB  50000
#define K_DIM    1024
#define LDOUT    50512
#define S_LEN    512
#define C_VOCAB  512

typedef __attribute__((ext_vector_type(8))) short frag8;   // 8 bf16 (4 VGPRs)
typedef __attribute__((ext_vector_type(4))) float facc4;   // 4 fp32 acc

__device__ __forceinline__ ushort f2bf(float f) {
    union { float f; unsigned u; } v; v.f = f;
    unsigned r = v.u + 0x7FFFu + ((v.u >> 16) & 1u);   // RNE
    return (ushort)(r >> 16);
}

// async global->LDS, 16B per lane; LDS dest is wave-uniform base + lane*16
#define GLDS16(gp, lp) __builtin_amdgcn_global_load_lds( \
    (const __attribute__((address_space(1))) void*)(gp), \
    (__attribute__((address_space(3))) void*)(lp), 16, 0, 0)

// -------- convert W fp32 -> bf16 into workspace (path A only) --------
__global__ __launch_bounds__(256) void cvtw_kernel(const float* __restrict__ W,
                                                   ushort* __restrict__ Wbf) {
    size_t i = ((size_t)blockIdx.x * 256 + threadIdx.x) * 8;   // exact: 25000 blocks
    float4 a = *(const float4*)(W + i);
    float4 b = *(const float4*)(W + i + 4);
    ushort4 p0 = { f2bf(a.x), f2bf(a.y), f2bf(a.z), f2bf(a.w) };
    ushort4 p1 = { f2bf(b.x), f2bf(b.y), f2bf(b.z), f2bf(b.w) };
    *(ushort4*)(&Wbf[i]) = p0;
    *(ushort4*)(&Wbf[i + 4]) = p1;
}

// -------- p_copy = sigmoid(hidden . w_copy + b_copy); also zero rowsum;
//          optionally convert hidden row to bf16 --------
template<bool PRE>
__global__ __launch_bounds__(256) void pcopy_kernel(const float* __restrict__ hidden,
                                                    const float* __restrict__ w_copy,
                                                    const float* __restrict__ b_copy,
                                                    float* __restrict__ p_copy,
                                                    float* __restrict__ rowsum,
                                                    ushort* __restrict__ Abf) {
    int m = blockIdx.x;
    int tid = threadIdx.x;
    float4 h = *(const float4*)(&hidden[(size_t)m * K_DIM + tid * 4]);
    float4 w = *(const float4*)(&w_copy[tid * 4]);
    if (PRE) {
        ushort4 pk = { f2bf(h.x), f2bf(h.y), f2bf(h.z), f2bf(h.w) };
        *(ushort4*)(&Abf[(size_t)m * K_DIM + tid * 4]) = pk;
    }
    float s = h.x * w.x + h.y * w.y + h.z * w.z + h.w * w.w;
    #pragma unroll
    for (int off = 32; off; off >>= 1) s += __shfl_down(s, off);
    __shared__ float wsum[4];
    if ((tid & 63) == 0) wsum[tid >> 6] = s;
    __syncthreads();
    if (tid == 0) {
        float tot = wsum[0] + wsum[1] + wsum[2] + wsum[3] + b_copy[0];
        p_copy[m] = 1.0f / (1.0f + __expf(-tot));
        rowsum[m] = 0.0f;
    }
}

// -------- main GEMM: out[m,n<50000] = exp(hidden@W.T + b), rowsum += --------
// 128x128 tile, BK=32, 4 waves (2x2), each wave 4x4 of 16x16x32 bf16 MFMA.
// PRE path: global_load_lds width-16 staging (m97 structure).
// Block swizzle: XCD-chunked, m-tile fastest -> each 256KB W-tile reused 16x in one L2.
template<bool PRE>
__global__ __launch_bounds__(256, 2)
void gemm_softmax_kernel(const float* __restrict__ hidden,
                         const float* __restrict__ W,
                         const ushort* __restrict__ Abf,
                         const ushort* __restrict__ Wbf,
                         const float* __restrict__ bias,
                         float* __restrict__ out,
                         float* __restrict__ rowsum,
                         const int* __restrict__ pad_idx_p) {
    __shared__ ushort As[128 * 32];
    __shared__ ushort Bs[128 * 32];
    const int tid = threadIdx.x;

    // XCD-aware bijective swizzle (nwg = 6256, 6256 % 8 == 0 -> simple form OK)
    const int id  = blockIdx.y * gridDim.x + blockIdx.x;   // dispatch order, x fastest
    const int nwg = gridDim.x * gridDim.y;                 // 6256
    const int cpx = nwg >> 3;                              // 782 per XCD
    const int swz = (id & 7) * cpx + (id >> 3);
    const int m0 = (swz & 15) * 128;                       // m-tile fastest within chunk
    const int n0 = (swz >> 4) * 128;                       // 0..390

    const int wave = tid >> 6, lane = tid & 63;
    const int wr = wave >> 1, wc = wave & 1;
    const int q = lane >> 4, ln = lane & 15;
    const int pad_idx = pad_idx_p[0];

    facc4 acc[4][4];
    #pragma unroll
    for (int i = 0; i < 4; ++i)
        #pragma unroll
        for (int j = 0; j < 4; ++j)
            acc[i][j] = (facc4){0.f, 0.f, 0.f, 0.f};

    if (PRE) {
        // staging geometry: per wave-call, 64 lanes x 16B = 1KB = 16 rows of 64B.
        // lane l -> row (l>>2), col-ushort (l&3)*8  (row-major [128][32] bf16 tile)
        const int lrow = lane >> 2;          // 0..15
        const int lcol = (lane & 3) * 8;     // ushort offset within row
        for (int kt = 0; kt < K_DIM; kt += 32) {
            __syncthreads();                 // previous iter's frag reads done
            #pragma unroll
            for (int c = 0; c < 2; ++c) {
                const int crow = (wave * 2 + c) * 16;    // 16-row chunk per wave-call
                GLDS16(&Abf[(size_t)(m0 + crow + lrow) * K_DIM + kt + lcol],
                       &As[crow * 32]);
                GLDS16(&Wbf[(size_t)(n0 + crow + lrow) * K_DIM + kt + lcol],
                       &Bs[crow * 32]);
            }
            __syncthreads();                 // vmcnt(0) drain before use

            frag8 fa[4], fb[4];
            #pragma unroll
            for (int t = 0; t < 4; ++t) {
                fa[t] = *(const frag8*)(&As[(wr * 64 + t * 16 + ln) * 32 + q * 8]);
                fb[t] = *(const frag8*)(&Bs[(wc * 64 + t * 16 + ln) * 32 + q * 8]);
            }
            #pragma unroll
            for (int i = 0; i < 4; ++i)
                #pragma unroll
                for (int j = 0; j < 4; ++j)
                    acc[i][j] = __builtin_amdgcn_mfma_f32_16x16x32_bf16(fa[i], fb[j], acc[i][j], 0, 0, 0);
        }
    } else {
        const int sr = tid >> 2;      // 0..63 staging row
        const int sg = tid & 3;       // 0..3 staging group of 8 elems
        for (int kt = 0; kt < K_DIM; kt += 32) {
            __syncthreads();
            #pragma unroll
            for (int p = 0; p < 2; ++p) {
                int row = sr + p * 64;
                const float4 a0 = *(const float4*)(&hidden[(size_t)(m0 + row) * K_DIM + kt + sg * 8]);
                const float4 a1 = *(const float4*)(&hidden[(size_t)(m0 + row) * K_DIM + kt + sg * 8 + 4]);
                ushort4 pa0 = { f2bf(a0.x), f2bf(a0.y), f2bf(a0.z), f2bf(a0.w) };
                ushort4 pa1 = { f2bf(a1.x), f2bf(a1.y), f2bf(a1.z), f2bf(a1.w) };
                *(ushort4*)(&As[row * 32 + sg * 8])     = pa0;
                *(ushort4*)(&As[row * 32 + sg * 8 + 4]) = pa1;
                int wrow = n0 + row; if (wrow >= N_VOCAB) wrow = N_VOCAB - 1;
                const float4 b0 = *(const float4*)(&W[(size_t)wrow * K_DIM + kt + sg * 8]);
                const float4 b1 = *(const float4*)(&W[(size_t)wrow * K_DIM + kt + sg * 8 + 4]);
                ushort4 pb0 = { f2bf(b0.x), f2bf(b0.y), f2bf(b0.z), f2bf(b0.w) };
                ushort4 pb1 = { f2bf(b1.x), f2bf(b1.y), f2bf(b1.z), f2bf(b1.w) };
                *(ushort4*)(&Bs[row * 32 + sg * 8])     = pb0;
                *(ushort4*)(&Bs[row * 32 + sg * 8 + 4]) = pb1;
            }
            __syncthreads();

            frag8 fa[4], fb[4];
            #pragma unroll
            for (int t = 0; t < 4; ++t) {
                fa[t] = *(const frag8*)(&As[(wr * 64 + t * 16 + ln) * 32 + q * 8]);
                fb[t] = *(const frag8*)(&Bs[(wc * 64 + t * 16 + ln) * 32 + q * 8]);
            }
            #pragma unroll
            for (int i = 0; i < 4; ++i)
                #pragma unroll
                for (int j = 0; j < 4; ++j)
                    acc[i][j] = __builtin_amdgcn_mfma_f32_16x16x32_bf16(fa[i], fb[j], acc[i][j], 0, 0, 0);
        }
    }

    // epilogue: e = exp(logit + bias) (0 at pad / OOB), store, row-sum reduce
    float bvals[4];
    #pragma unroll
    for (int j = 0; j < 4; ++j) {
        int n = n0 + wc * 64 + j * 16 + ln;
        bvals[j] = (n < N_VOCAB) ? bias[n] : 0.0f;
    }
    float rsum[16];
    #pragma unroll
    for (int i = 0; i < 4; ++i) {          // ti sub-tile
        #pragma unroll
        for (int r = 0; r < 4; ++r) {      // acc reg -> row
            int m = m0 + wr * 64 + i * 16 + q * 4 + r;
            float rs = 0.0f;
            #pragma unroll
            for (int j = 0; j < 4; ++j) {  // tj sub-tile -> col
                int n = n0 + wc * 64 + j * 16 + ln;
                float e = 0.0f;
                if (n < N_VOCAB && n != pad_idx) e = __expf(acc[i][j][r] + bvals[j]);
                if (n < N_VOCAB) out[(size_t)m * LDOUT + n] = e;
                rs += e;
            }
            rsum[i * 4 + r] = rs;
        }
    }
    #pragma unroll
    for (int s = 0; s < 16; ++s) {
        float v = rsum[s];
        v += __shfl_xor(v, 1);
        v += __shfl_xor(v, 2);
        v += __shfl_xor(v, 4);
        v += __shfl_xor(v, 8);
        rsum[s] = v;
    }
    if (ln == 0) {
        #pragma unroll
        for (int s = 0; s < 16; ++s) {
            int i = s >> 2, r = s & 3;
            int m = m0 + wr * 64 + i * 16 + q * 4 + r;
            atomicAdd(&rowsum[m], rsum[s]);
        }
    }
}

// -------- normalize + gate: out[m, :50000] *= (1-p_copy)/rowsum --------
__global__ __launch_bounds__(256) void scale_kernel(float* __restrict__ out,
                                                    const float* __restrict__ rowsum,
                                                    const float* __restrict__ p_copy) {
    int m = blockIdx.x;
    float sc = (1.0f - p_copy[m]) / rowsum[m];
    float4* row = (float4*)(out + (size_t)m * LDOUT);
    for (int t = threadIdx.x; t < N_VOCAB / 4; t += 256) {
        float4 v = row[t];
        v.x *= sc; v.y *= sc; v.z *= sc; v.w *= sc;
        row[t] = v;
    }
}

// -------- copy_prob: out[m, 50000+c] = p_copy[m] * sum_s attn[m,s]*src_map[b,s,c] --------
__global__ __launch_bounds__(256) void copyprob_kernel(const float* __restrict__ attn,
                                                       const float* __restrict__ src_map,
                                                       const float* __restrict__ p_copy,
                                                       float* __restrict__ out) {
    __shared__ float la[16 * S_LEN];
    int b = blockIdx.x;          // 0..15
    int mt0 = b * 128 + blockIdx.y * 16;   // global row base (16 rows per block)
    for (int idx = threadIdx.x; idx < 16 * S_LEN; idx += 256) {
        int t = idx >> 9, s = idx & 511;
        la[idx] = attn[(size_t)(mt0 + t) * S_LEN + s];
    }
    __syncthreads();
    int c0 = threadIdx.x, c1 = threadIdx.x + 256;
    float acc0[16], acc1[16];
    #pragma unroll
    for (int t = 0; t < 16; ++t) { acc0[t] = 0.f; acc1[t] = 0.f; }
    const float* sm = src_map + (size_t)b * S_LEN * C_VOCAB;
    for (int s = 0; s < S_LEN; ++s) {
        float v0 = sm[s * C_VOCAB + c0];
        float v1 = sm[s * C_VOCAB + c1];
        #pragma unroll
        for (int t = 0; t < 16; ++t) {
            float a = la[t * S_LEN + s];
            acc0[t] += a * v0;
            acc1[t] += a * v1;
        }
    }
    #pragma unroll
    for (int t = 0; t < 16; ++t) {
        int m = mt0 + t;
        float pc = p_copy[m];
        out[(size_t)m * LDOUT + N_VOCAB + c0] = pc * acc0[t];
        out[(size_t)m * LDOUT + N_VOCAB + c1] = pc * acc1[t];
    }
}

extern "C" void kernel_launch(void* const* d_in, const int* in_sizes, int n_in,
                              void* d_out, int out_size, void* d_ws, size_t ws_size,
                              hipStream_t stream) {
    const float* hidden  = (const float*)d_in[0];
    const float* attn    = (const float*)d_in[1];
    const float* src_map = (const float*)d_in[2];
    const float* W       = (const float*)d_in[3];
    const float* bias    = (const float*)d_in[4];
    const float* w_copy  = (const float*)d_in[5];
    const float* b_copy  = (const float*)d_in[6];
    const int*   pad_p   = (const int*)d_in[7];
    float* out = (float*)d_out;

    const size_t WBF_BYTES = (size_t)50048 * K_DIM * 2;  // padded to tile edge
    const size_t ABF_BYTES = (size_t)M_ROWS * K_DIM * 2;
    const size_t NEED = WBF_BYTES + ABF_BYTES + (size_t)M_ROWS * 4 * 2;
    char* wsc = (char*)d_ws;
    bool pre = (ws_size >= NEED);

    ushort* Wbf = (ushort*)wsc;
    ushort* Abf = (ushort*)(wsc + WBF_BYTES);
    float* rowsum;
    if (pre) rowsum = (float*)(wsc + WBF_BYTES + ABF_BYTES);
    else     rowsum = (float*)wsc;           // fallback needs only 16 KB
    float* p_copy = rowsum + M_ROWS;

    dim3 gemm_grid((N_VOCAB + 127) / 128, M_ROWS / 128);  // 391 x 16

    if (pre) {
        cvtw_kernel<<<(N_VOCAB * K_DIM) / (256 * 8), 256, 0, stream>>>(W, Wbf);
        pcopy_kernel<true><<<M_ROWS, 256, 0, stream>>>(hidden, w_copy, b_copy, p_copy, rowsum, Abf);
        gemm_softmax_kernel<true><<<gemm_grid, 256, 0, stream>>>(hidden, W, Abf, Wbf, bias, out, rowsum, pad_p);
    } else {
        pcopy_kernel<false><<<M_ROWS, 256, 0, stream>>>(hidden, w_copy, b_copy, p_copy, rowsum, nullptr);
        gemm_softmax_kernel<false><<<gemm_grid, 256, 0, stream>>>(hidden, W, nullptr, nullptr, bias, out, rowsum, pad_p);
    }
    scale_kernel<<<M_ROWS, 256, 0, stream>>>(out, rowsum, p_copy);
    copyprob_kernel<<<dim3(16, 8), 256, 0, stream>>>(attn, src_map, p_copy, out);
}

// Round 2
// 1038.047 us; speedup vs baseline: 1.3440x; 1.0786x over previous
//
#include <hip/hip_runtime.h>
#include <hip/hip_bf16.h>
#include <math.h>

#define M_ROWS   2048
#define N_VOCAB  50000
#define K_DIM    1024
#define LDOUT    50512
#define S_LEN    512
#define C_VOCAB  512

typedef __attribute__((ext_vector_type(8))) short frag8;   // 8 bf16 (4 VGPRs)
typedef __attribute__((ext_vector_type(4))) float facc4;   // 4 fp32 acc

__device__ __forceinline__ ushort f2bf(float f) {
    union { float f; unsigned u; } v; v.f = f;
    unsigned r = v.u + 0x7FFFu + ((v.u >> 16) & 1u);   // RNE
    return (ushort)(r >> 16);
}

// async global->LDS, 16B per lane; LDS dest is wave-uniform base + lane*16
#define GLDS16(gp, lp) __builtin_amdgcn_global_load_lds( \
    (const __attribute__((address_space(1))) void*)(gp), \
    (__attribute__((address_space(3))) void*)(lp), 16, 0, 0)

// -------- convert W fp32 -> bf16 into workspace (path A only) --------
__global__ __launch_bounds__(256) void cvtw_kernel(const float* __restrict__ W,
                                                   ushort* __restrict__ Wbf) {
    size_t i = ((size_t)blockIdx.x * 256 + threadIdx.x) * 8;   // exact: 25000 blocks
    float4 a = *(const float4*)(W + i);
    float4 b = *(const float4*)(W + i + 4);
    ushort4 p0 = { f2bf(a.x), f2bf(a.y), f2bf(a.z), f2bf(a.w) };
    ushort4 p1 = { f2bf(b.x), f2bf(b.y), f2bf(b.z), f2bf(b.w) };
    *(ushort4*)(&Wbf[i]) = p0;
    *(ushort4*)(&Wbf[i + 4]) = p1;
}

// -------- p_copy = sigmoid(hidden . w_copy + b_copy); also zero rowsum;
//          optionally convert hidden row to bf16 --------
template<bool PRE>
__global__ __launch_bounds__(256) void pcopy_kernel(const float* __restrict__ hidden,
                                                    const float* __restrict__ w_copy,
                                                    const float* __restrict__ b_copy,
                                                    float* __restrict__ p_copy,
                                                    float* __restrict__ rowsum,
                                                    ushort* __restrict__ Abf) {
    int m = blockIdx.x;
    int tid = threadIdx.x;
    float4 h = *(const float4*)(&hidden[(size_t)m * K_DIM + tid * 4]);
    float4 w = *(const float4*)(&w_copy[tid * 4]);
    if (PRE) {
        ushort4 pk = { f2bf(h.x), f2bf(h.y), f2bf(h.z), f2bf(h.w) };
        *(ushort4*)(&Abf[(size_t)m * K_DIM + tid * 4]) = pk;
    }
    float s = h.x * w.x + h.y * w.y + h.z * w.z + h.w * w.w;
    #pragma unroll
    for (int off = 32; off; off >>= 1) s += __shfl_down(s, off);
    __shared__ float wsum[4];
    if ((tid & 63) == 0) wsum[tid >> 6] = s;
    __syncthreads();
    if (tid == 0) {
        float tot = wsum[0] + wsum[1] + wsum[2] + wsum[3] + b_copy[0];
        p_copy[m] = 1.0f / (1.0f + __expf(-tot));
        rowsum[m] = 0.0f;
    }
}

// -------- main GEMM: out[m,n<50000] = exp(hidden@W.T + b), rowsum += --------
// 128x128 tile, BK=32, 4 waves (2x2), each wave 4x4 of 16x16x32 bf16 MFMA.
// PRE path: global_load_lds width-16 staging (m97 structure).
// Block swizzle: XCD-chunked, m-tile fastest -> each 256KB W-tile reused 16x in one L2.
template<bool PRE>
__global__ __launch_bounds__(256, 2)
void gemm_softmax_kernel(const float* __restrict__ hidden,
                         const float* __restrict__ W,
                         const ushort* __restrict__ Abf,
                         const ushort* __restrict__ Wbf,
                         const float* __restrict__ bias,
                         float* __restrict__ out,
                         float* __restrict__ rowsum,
                         const int* __restrict__ pad_idx_p) {
    __shared__ ushort As[128 * 32];
    __shared__ ushort Bs[128 * 32];
    const int tid = threadIdx.x;

    // XCD-aware bijective swizzle (nwg = 6256, 6256 % 8 == 0 -> simple form OK)
    const int id  = blockIdx.y * gridDim.x + blockIdx.x;   // dispatch order, x fastest
    const int nwg = gridDim.x * gridDim.y;                 // 6256
    const int cpx = nwg >> 3;                              // 782 per XCD
    const int swz = (id & 7) * cpx + (id >> 3);
    const int m0 = (swz & 15) * 128;                       // m-tile fastest within chunk
    const int n0 = (swz >> 4) * 128;                       // 0..390

    const int wave = tid >> 6, lane = tid & 63;
    const int wr = wave >> 1, wc = wave & 1;
    const int q = lane >> 4, ln = lane & 15;
    const int pad_idx = pad_idx_p[0];

    facc4 acc[4][4];
    #pragma unroll
    for (int i = 0; i < 4; ++i)
        #pragma unroll
        for (int j = 0; j < 4; ++j)
            acc[i][j] = (facc4){0.f, 0.f, 0.f, 0.f};

    if (PRE) {
        // staging geometry: per wave-call, 64 lanes x 16B = 1KB = 16 rows of 64B.
        // lane l -> row (l>>2), col-ushort (l&3)*8  (row-major [128][32] bf16 tile)
        const int lrow = lane >> 2;          // 0..15
        const int lcol = (lane & 3) * 8;     // ushort offset within row
        for (int kt = 0; kt < K_DIM; kt += 32) {
            __syncthreads();                 // previous iter's frag reads done
            #pragma unroll
            for (int c = 0; c < 2; ++c) {
                const int crow = (wave * 2 + c) * 16;    // 16-row chunk per wave-call
                GLDS16(&Abf[(size_t)(m0 + crow + lrow) * K_DIM + kt + lcol],
                       &As[crow * 32]);
                GLDS16(&Wbf[(size_t)(n0 + crow + lrow) * K_DIM + kt + lcol],
                       &Bs[crow * 32]);
            }
            __syncthreads();                 // vmcnt(0) drain before use

            frag8 fa[4], fb[4];
            #pragma unroll
            for (int t = 0; t < 4; ++t) {
                fa[t] = *(const frag8*)(&As[(wr * 64 + t * 16 + ln) * 32 + q * 8]);
                fb[t] = *(const frag8*)(&Bs[(wc * 64 + t * 16 + ln) * 32 + q * 8]);
            }
            #pragma unroll
            for (int i = 0; i < 4; ++i)
                #pragma unroll
                for (int j = 0; j < 4; ++j)
                    acc[i][j] = __builtin_amdgcn_mfma_f32_16x16x32_bf16(fa[i], fb[j], acc[i][j], 0, 0, 0);
        }
    } else {
        const int sr = tid >> 2;      // 0..63 staging row
        const int sg = tid & 3;       // 0..3 staging group of 8 elems
        for (int kt = 0; kt < K_DIM; kt += 32) {
            __syncthreads();
            #pragma unroll
            for (int p = 0; p < 2; ++p) {
                int row = sr + p * 64;
                const float4 a0 = *(const float4*)(&hidden[(size_t)(m0 + row) * K_DIM + kt + sg * 8]);
                const float4 a1 = *(const float4*)(&hidden[(size_t)(m0 + row) * K_DIM + kt + sg * 8 + 4]);
                ushort4 pa0 = { f2bf(a0.x), f2bf(a0.y), f2bf(a0.z), f2bf(a0.w) };
                ushort4 pa1 = { f2bf(a1.x), f2bf(a1.y), f2bf(a1.z), f2bf(a1.w) };
                *(ushort4*)(&As[row * 32 + sg * 8])     = pa0;
                *(ushort4*)(&As[row * 32 + sg * 8 + 4]) = pa1;
                int wrow = n0 + row; if (wrow >= N_VOCAB) wrow = N_VOCAB - 1;
                const float4 b0 = *(const float4*)(&W[(size_t)wrow * K_DIM + kt + sg * 8]);
                const float4 b1 = *(const float4*)(&W[(size_t)wrow * K_DIM + kt + sg * 8 + 4]);
                ushort4 pb0 = { f2bf(b0.x), f2bf(b0.y), f2bf(b0.z), f2bf(b0.w) };
                ushort4 pb1 = { f2bf(b1.x), f2bf(b1.y), f2bf(b1.z), f2bf(b1.w) };
                *(ushort4*)(&Bs[row * 32 + sg * 8])     = pb0;
                *(ushort4*)(&Bs[row * 32 + sg * 8 + 4]) = pb1;
            }
            __syncthreads();

            frag8 fa[4], fb[4];
            #pragma unroll
            for (int t = 0; t < 4; ++t) {
                fa[t] = *(const frag8*)(&As[(wr * 64 + t * 16 + ln) * 32 + q * 8]);
                fb[t] = *(const frag8*)(&Bs[(wc * 64 + t * 16 + ln) * 32 + q * 8]);
            }
            #pragma unroll
            for (int i = 0; i < 4; ++i)
                #pragma unroll
                for (int j = 0; j < 4; ++j)
                    acc[i][j] = __builtin_amdgcn_mfma_f32_16x16x32_bf16(fa[i], fb[j], acc[i][j], 0, 0, 0);
        }
    }

    // epilogue: e = exp(logit + bias) (0 at pad / OOB), store, row-sum reduce
    float bvals[4];
    #pragma unroll
    for (int j = 0; j < 4; ++j) {
        int n = n0 + wc * 64 + j * 16 + ln;
        bvals[j] = (n < N_VOCAB) ? bias[n] : 0.0f;
    }
    float rsum[16];
    #pragma unroll
    for (int i = 0; i < 4; ++i) {          // ti sub-tile
        #pragma unroll
        for (int r = 0; r < 4; ++r) {      // acc reg -> row
            int m = m0 + wr * 64 + i * 16 + q * 4 + r;
            float rs = 0.0f;
            #pragma unroll
            for (int j = 0; j < 4; ++j) {  // tj sub-tile -> col
                int n = n0 + wc * 64 + j * 16 + ln;
                float e = 0.0f;
                if (n < N_VOCAB && n != pad_idx) e = __expf(acc[i][j][r] + bvals[j]);
                if (n < N_VOCAB) out[(size_t)m * LDOUT + n] = e;
                rs += e;
            }
            rsum[i * 4 + r] = rs;
        }
    }
    #pragma unroll
    for (int s = 0; s < 16; ++s) {
        float v = rsum[s];
        v += __shfl_xor(v, 1);
        v += __shfl_xor(v, 2);
        v += __shfl_xor(v, 4);
        v += __shfl_xor(v, 8);
        rsum[s] = v;
    }
    if (ln == 0) {
        #pragma unroll
        for (int s = 0; s < 16; ++s) {
            int i = s >> 2, r = s & 3;
            int m = m0 + wr * 64 + i * 16 + q * 4 + r;
            atomicAdd(&rowsum[m], rsum[s]);
        }
    }
}

// -------- normalize + gate: out[m, :50000] *= (1-p_copy)/rowsum --------
// 2D grid: (4 column chunks, 2048 rows) = 8192 blocks -> 32 blocks/CU TLP.
__global__ __launch_bounds__(256) void scale_kernel(float* __restrict__ out,
                                                    const float* __restrict__ rowsum,
                                                    const float* __restrict__ p_copy) {
    int m = blockIdx.y;
    int chunk = blockIdx.x;                  // 0..3, 3125 float4 each (12500 total)
    float sc = (1.0f - p_copy[m]) / rowsum[m];
    float4* row = (float4*)(out + (size_t)m * LDOUT);
    int end = (chunk + 1) * 3125;
    for (int t = chunk * 3125 + threadIdx.x; t < end; t += 256) {
        float4 v = row[t];
        v.x *= sc; v.y *= sc; v.z *= sc; v.w *= sc;
        row[t] = v;
    }
}

// -------- copy_prob: out[m, 50000+c] = p_copy[m] * sum_s attn[m,s]*src_map[b,s,c] --------
// grid (16 b, 8 rowgroups of 16, 4 col chunks of 128) = 512 blocks.
// thread: c = cc*128 + (tid&127), owns 8 rows (half = tid>>7).
__global__ __launch_bounds__(256) void copyprob_kernel(const float* __restrict__ attn,
                                                       const float* __restrict__ src_map,
                                                       const float* __restrict__ p_copy,
                                                       float* __restrict__ out) {
    __shared__ float la[16 * S_LEN];         // 32 KB
    int b   = blockIdx.x;                    // 0..15
    int mt0 = b * 128 + blockIdx.y * 16;     // 16-row group
    int c   = blockIdx.z * 128 + (threadIdx.x & 127);
    int half = threadIdx.x >> 7;             // 0/1 -> rows 0..7 / 8..15
    for (int idx = threadIdx.x; idx < 16 * S_LEN; idx += 256) {
        int t = idx >> 9, s = idx & 511;
        la[idx] = attn[(size_t)(mt0 + t) * S_LEN + s];
    }
    __syncthreads();
    float acc[8];
    #pragma unroll
    for (int r = 0; r < 8; ++r) acc[r] = 0.f;
    const float* sm = src_map + (size_t)b * S_LEN * C_VOCAB;
    const float* lar = &la[(half * 8) * S_LEN];
    for (int s = 0; s < S_LEN; ++s) {
        float v = sm[(size_t)s * C_VOCAB + c];
        #pragma unroll
        for (int r = 0; r < 8; ++r)
            acc[r] += lar[r * S_LEN + s] * v;   // LDS broadcast (same addr per wave)
    }
    #pragma unroll
    for (int r = 0; r < 8; ++r) {
        int m = mt0 + half * 8 + r;
        out[(size_t)m * LDOUT + N_VOCAB + c] = p_copy[m] * acc[r];
    }
}

extern "C" void kernel_launch(void* const* d_in, const int* in_sizes, int n_in,
                              void* d_out, int out_size, void* d_ws, size_t ws_size,
                              hipStream_t stream) {
    const float* hidden  = (const float*)d_in[0];
    const float* attn    = (const float*)d_in[1];
    const float* src_map = (const float*)d_in[2];
    const float* W       = (const float*)d_in[3];
    const float* bias    = (const float*)d_in[4];
    const float* w_copy  = (const float*)d_in[5];
    const float* b_copy  = (const float*)d_in[6];
    const int*   pad_p   = (const int*)d_in[7];
    float* out = (float*)d_out;

    const size_t WBF_BYTES = (size_t)50048 * K_DIM * 2;  // padded to tile edge
    const size_t ABF_BYTES = (size_t)M_ROWS * K_DIM * 2;
    const size_t NEED = WBF_BYTES + ABF_BYTES + (size_t)M_ROWS * 4 * 2;
    char* wsc = (char*)d_ws;
    bool pre = (ws_size >= NEED);

    ushort* Wbf = (ushort*)wsc;
    ushort* Abf = (ushort*)(wsc + WBF_BYTES);
    float* rowsum;
    if (pre) rowsum = (float*)(wsc + WBF_BYTES + ABF_BYTES);
    else     rowsum = (float*)wsc;           // fallback needs only 16 KB
    float* p_copy = rowsum + M_ROWS;

    dim3 gemm_grid((N_VOCAB + 127) / 128, M_ROWS / 128);  // 391 x 16

    if (pre) {
        cvtw_kernel<<<(N_VOCAB * K_DIM) / (256 * 8), 256, 0, stream>>>(W, Wbf);
        pcopy_kernel<true><<<M_ROWS, 256, 0, stream>>>(hidden, w_copy, b_copy, p_copy, rowsum, Abf);
        gemm_softmax_kernel<true><<<gemm_grid, 256, 0, stream>>>(hidden, W, Abf, Wbf, bias, out, rowsum, pad_p);
    } else {
        pcopy_kernel<false><<<M_ROWS, 256, 0, stream>>>(hidden, w_copy, b_copy, p_copy, rowsum, nullptr);
        gemm_softmax_kernel<false><<<gemm_grid, 256, 0, stream>>>(hidden, W, nullptr, nullptr, bias, out, rowsum, pad_p);
    }
    scale_kernel<<<dim3(4, M_ROWS), 256, 0, stream>>>(out, rowsum, p_copy);
    copyprob_kernel<<<dim3(16, 8, 4), 256, 0, stream>>>(attn, src_map, p_copy, out);
}